// Round 4
// baseline (117.249 us; speedup 1.0000x reference)
//
#include <hip/hip_runtime.h>
#include <hip/hip_bf16.h>

// B=64, M=16, T=2048, L=64, K=32, N=1985
#define B_ 64
#define M_ 16
#define T_ 2048
#define L_ 64
#define K_ 32
#define N_ (T_ - L_ + 1)   // 1985
#define TN 64              // n-positions per block
#define NT_ 32             // n-tiles (grid x)
#define NTH 256            // 4 waves: wave w owns n-subtile [16w,16w+16), both k-tiles
#define XROW 144           // per-plane row elems; need j<=123. 144 elems = 72 dw
                           // == 8 (mod 32) -> planes at bank offsets {0,8,16,24}:
                           // uniform 4 touches/bank = the 512B/wave floor.
#define STSTR 72           // st row stride elems (16B-aligned b128 reads)
// Blocked pen layout: pen[k][nt][m][64], nt = n-tile, padded to n=2048.
// index = k*32768 + nt*1024 + m*64 + nin. Full 128B-line utilization per block,
// no bounds guards anywhere in the main kernel's m-loop.
#define PENK (NT_ * M_ * 64)        // 32768 floats per k
#define PENSZ (K_ * PENK)           // 1,048,576 floats = 4 MB

typedef __attribute__((ext_vector_type(8))) short bf16x8;
typedef __attribute__((ext_vector_type(4))) float f32x4;

__device__ __forceinline__ unsigned short f2bf(float f) {
    __hip_bfloat16 h = __float2bfloat16(f);
    return __builtin_bit_cast(unsigned short, h);
}

__device__ __forceinline__ float elu_pen(float p) {
    return (p < 0.f) ? (2.f - p) : (__expf(-p) + 1.f);   // elu(-p) + 2
}

// Fused init: out = +inf bits, ss[k] = sum shp^2, pen in blocked layout.
__global__ void pen_init_kernel(const float* __restrict__ pmap,
                                const float* __restrict__ shp,
                                float* __restrict__ pen,
                                float* __restrict__ ss_ws,
                                unsigned* __restrict__ out) {
    const int gid = blockIdx.x * 256 + threadIdx.x;
    if (gid < B_ * K_) out[gid] = 0x7F800000u;  // +inf
    if (gid < K_) {
        float s = 0.f;
        for (int l = 0; l < L_; ++l) { float v = shp[gid * L_ + l]; s = fmaf(v, v, s); }
        ss_ws[gid] = s;
    }
    if (gid < PENSZ / 4) {
        const int o = gid * 4;
        const int nin = o & 63;
        const int m   = (o >> 6) & 15;
        const int nt  = (o >> 10) & 31;
        const int k   = o >> 15;
        const int n   = nt * TN + nin;
        const float* src = pmap + ((size_t)k * M_ + m) * N_ + n;
        float p[4];
        if (n + 3 < N_) {
            float4 v = *(const float4*)src;
            p[0] = v.x; p[1] = v.y; p[2] = v.z; p[3] = v.w;
        } else {
#pragma unroll
            for (int i = 0; i < 4; ++i) p[i] = (n + i < N_) ? src[i] : 0.f;
        }
        float4 r;
        r.x = elu_pen(p[0]); r.y = elu_pen(p[1]);
        r.z = elu_pen(p[2]); r.w = elu_pen(p[3]);
        *(float4*)(pen + o) = r;
    }
}

// LDS: 18432 + 4608 + 4096 = 27136 B; x6 = 162816 <= 163840 -> 6 blocks/CU.
// VGPR must stay <= 64 (waves/CU halves at 64) — r3's rotate pipeline measured 48.
__global__ __launch_bounds__(NTH, 4)
void shapelet_mfma_kernel(const float* __restrict__ x,
                          const float* __restrict__ shp,
                          const float* __restrict__ pen,
                          const float* __restrict__ ss_ws,
                          unsigned* __restrict__ out) {
    __shared__ __align__(16) unsigned short xbuf4[M_][4][XROW]; // 4 shifted bf16 planes
    __shared__ __align__(16) unsigned short st[K_][STSTR];      // shapelets bf16
    __shared__ __align__(16) float sqw[M_][TN];                 // fp32 sliding sum x^2

    const int tid = threadIdx.x;
    const int bx = blockIdx.x;
    const int n0 = bx * TN;
    const int b  = blockIdx.y;
    const bool fast = (n0 + 2 * TN <= T_);   // false only for last tile (n0=1984)

    // ---- per-lane MFMA coordinates (needed now for the pen prefetch) ----
    const int lane = tid & 63;
    const int w  = tid >> 6;       // wave -> n-subtile [16w, 16w+16)
    const int rl = lane & 15;      // A-row (n within subtile) / B-col (k within tile)
    const int q  = lane >> 4;      // quad
    const int sp = rl & 3;                          // shift plane
    const int e0 = 16 * w + 8 * q + (rl & ~3);      // 4-aligned elem base (max 84)
    const int eq = e0 >> 2;                         // uint2 index (max 21; +9 fits)
    const int nrow = n0 + 16 * w + 4 * q;           // lane's 4 output rows: nrow + reg

    const float ssk0 = ss_ws[rl], ssk1 = ss_ws[16 + rl];

    // Blocked pen: rows of 64 floats per m; lane reads nin = 16w+4q .. +3.
    const float* pb0 = pen + (size_t)rl * PENK + (size_t)bx * (M_ * 64) + (16 * w + 4 * q);
    const float* pb1 = pb0 + (size_t)16 * PENK;   // k = rl + 16

    // ---- prefetch pen group 0 (m=0,1) BEFORE staging: latency hides under
    //      the staging HBM loads instead of being exposed after the barrier ----
    float4 pa0 = *(const float4*)(pb0);
    float4 pa1 = *(const float4*)(pb1);
    float4 pc0 = *(const float4*)(pb0 + 64);
    float4 pc1 = *(const float4*)(pb1 + 64);

    // ---- wave-specialized staging ----
    if (tid < 128) {
        // waves 0-1: sqw fp32 sliding window: 8 threads per m, 8 n each
        const int m = tid >> 3, j0 = (tid & 7) * 8;
        const float* xr = x + ((size_t)b * M_ + m) * T_ + n0;
        float s = 0.f;
        if (fast) {
#pragma unroll
            for (int qd = 0; qd < 16; ++qd) {
                float4 v = *(const float4*)(xr + j0 + qd * 4);
                s = fmaf(v.x, v.x, s); s = fmaf(v.y, v.y, s);
                s = fmaf(v.z, v.z, s); s = fmaf(v.w, v.w, s);
            }
            sqw[m][j0] = s;
#pragma unroll
            for (int d = 1; d < 8; ++d) {
                float a = xr[j0 + d + L_ - 1], r = xr[j0 + d - 1];
                s += a * a - r * r;
                sqw[m][j0 + d] = s;
            }
        } else {
            for (int l = 0; l < L_; ++l) {
                float v = (n0 + j0 + l < T_) ? xr[j0 + l] : 0.f;
                s = fmaf(v, v, s);
            }
            sqw[m][j0] = s;
            for (int d = 1; d < 8; ++d) {
                float a = (n0 + j0 + d + L_ - 1 < T_) ? xr[j0 + d + L_ - 1] : 0.f;
                float r = (n0 + j0 + d - 1 < T_) ? xr[j0 + d - 1] : 0.f;
                s += a * a - r * r;
                sqw[m][j0 + d] = s;
            }
        }
    } else {
        // waves 2-3: x -> 4 shifted bf16 planes (496 items) + shapelets (512 items)
        const int t2 = tid - 128;
        const float* xb = x + ((size_t)b * M_) * T_ + n0;
        for (int g = t2; g < M_ * 31; g += 128) {
            const int m = g / 31, j4 = (g - m * 31) * 4;     // j4 in {0,4,...,120}
            const float* src = xb + m * T_ + j4;
            float h[8];
            if (fast) {
                float4 v0 = *(const float4*)src;
                float4 v1 = *(const float4*)(src + 4);
                h[0] = v0.x; h[1] = v0.y; h[2] = v0.z; h[3] = v0.w;
                h[4] = v1.x; h[5] = v1.y; h[6] = v1.z; h[7] = v1.w;
            } else {
#pragma unroll
                for (int i = 0; i < 8; ++i)
                    h[i] = (n0 + j4 + i < T_) ? src[i] : 0.f;
            }
            unsigned short hb[8];
#pragma unroll
            for (int i = 0; i < 8; ++i) hb[i] = f2bf(h[i]);
#pragma unroll
            for (int s = 0; s < 4; ++s) {
                ushort4 sv = { hb[s], hb[s + 1], hb[s + 2], hb[s + 3] };
                *(ushort4*)&xbuf4[m][s][j4] = sv;
            }
        }
        for (int i = t2; i < K_ * 16; i += 128) {
            const int k = i >> 4, l4 = (i & 15) * 4;
            float4 v = *(const float4*)(shp + k * L_ + l4);
            ushort4 sv = { f2bf(v.x), f2bf(v.y), f2bf(v.z), f2bf(v.w) };
            *(ushort4*)&st[k][l4] = sv;
        }
    }
    __syncthreads();

    // b_frags (registers, whole kernel): st[16t+rl][8q+32h .. +7]
    bf16x8 bfr[2][2];
#pragma unroll
    for (int t = 0; t < 2; ++t)
#pragma unroll
        for (int h = 0; h < 2; ++h)
            bfr[t][h] = *(const bf16x8*)&st[16 * t + rl][8 * q + 32 * h];

    f32x4 wd0 = (f32x4)0.f, wd1 = (f32x4)0.f;
    const f32x4 zero = (f32x4)0.f;

    // One m-step: MFMA from LDS planes + penalized accumulate (pen precomputed).
    auto mstep = [&](int m, float4 pm0, float4 pm1) {
        const uint2* prow = (const uint2*)&xbuf4[m][sp][0];
        uint2 lo0 = prow[eq],     hi0 = prow[eq + 1];
        uint2 lo1 = prow[eq + 8], hi1 = prow[eq + 9];
        union { uint2 u2[2]; bf16x8 v; } fa0, fa1;
        fa0.u2[0] = lo0; fa0.u2[1] = hi0;
        fa1.u2[0] = lo1; fa1.u2[1] = hi1;

        f32x4 c0_ = __builtin_amdgcn_mfma_f32_16x16x32_bf16(fa0.v, bfr[0][0], zero, 0, 0, 0);
        c0_       = __builtin_amdgcn_mfma_f32_16x16x32_bf16(fa1.v, bfr[0][1], c0_, 0, 0, 0);
        f32x4 c1_ = __builtin_amdgcn_mfma_f32_16x16x32_bf16(fa0.v, bfr[1][0], zero, 0, 0, 0);
        c1_       = __builtin_amdgcn_mfma_f32_16x16x32_bf16(fa1.v, bfr[1][1], c1_, 0, 0, 0);

        const float pe0[4] = { pm0.x, pm0.y, pm0.z, pm0.w };
        const float pe1[4] = { pm1.x, pm1.y, pm1.z, pm1.w };
        f32x4 sq = *(const f32x4*)&sqw[m][16 * w + 4 * q];
#pragma unroll
        for (int r = 0; r < 4; ++r) {
            float u0 = fmaf(-2.f, c0_[r], sq[r] + ssk0);
            wd0[r] = fmaf(pe0[r], u0, wd0[r]);
            float u1 = fmaf(-2.f, c1_[r], sq[r] + ssk1);
            wd1[r] = fmaf(pe1[r], u1, wd1[r]);
        }
    };

    // Rolled m-pair loop, depth-2 rotating pen buffer (r3 structure: 48 VGPR, no
    // spill). Pen loads are unguarded (blocked layout is padded), so the last
    // tile runs the same fast m-loop; OOB rows are masked at the min.
    for (int mp = 0; mp < M_ / 2; ++mp) {
        const int m = 2 * mp;
        float4 c0 = pa0, c1 = pa1, d0 = pc0, d1 = pc1;
        if (mp + 1 < M_ / 2) {
            const float* q0 = pb0 + (size_t)(m + 2) * 64;
            const float* q1 = pb1 + (size_t)(m + 2) * 64;
            pa0 = *(const float4*)(q0);
            pa1 = *(const float4*)(q1);
            pc0 = *(const float4*)(q0 + 64);
            pc1 = *(const float4*)(q1 + 64);
        }
        mstep(m, c0, c1);
        mstep(m + 1, d0, d1);
    }

    // ---- min: 4 rows -> quads (shfl) -> LDS cross-wave -> 1 atomic per (b,k) ----
    __syncthreads();                       // sqw reads done; reuse as scratch
    float* red = (float*)&sqw[0][0];       // [4 waves][32]
#pragma unroll
    for (int t = 0; t < 2; ++t) {
        float lmin = __int_as_float(0x7F800000);
        const f32x4 wdv = t ? wd1 : wd0;
#pragma unroll
        for (int r = 0; r < 4; ++r)
            if (nrow + r < N_) lmin = fminf(lmin, wdv[r]);
        lmin = fminf(lmin, __shfl_xor(lmin, 16));
        lmin = fminf(lmin, __shfl_xor(lmin, 32));
        if (q == 0) red[w * 32 + t * 16 + rl] = lmin;
    }
    __syncthreads();
    if (tid < K_) {
        float v = fminf(fminf(red[tid], red[32 + tid]),
                        fminf(red[64 + tid], red[96 + tid]));
        atomicMin(out + (size_t)b * K_ + tid, __float_as_uint(fmaxf(v, 0.f)));
    }
}

extern "C" void kernel_launch(void* const* d_in, const int* in_sizes, int n_in,
                              void* d_out, int out_size, void* d_ws, size_t ws_size,
                              hipStream_t stream) {
    const float* x    = (const float*)d_in[0];   // (B, M, T)
    const float* shp  = (const float*)d_in[1];   // (K, L)
    const float* pmap = (const float*)d_in[2];   // (K, M, N)
    unsigned* out = (unsigned*)d_out;            // (B, K) float bits
    float* pen   = (float*)d_ws;                 // blocked pen, 4 MB
    float* ss_ws = pen + PENSZ;                  // (K,) fp32 sum shp^2

    // init covers out (+inf), ss, and blocked pen; no separate memset launch
    pen_init_kernel<<<dim3(PENSZ / 4 / 256), dim3(256), 0, stream>>>(
        pmap, shp, pen, ss_ws, out);

    dim3 grid(NT_, B_);                          // 32 x 64 = 2048 blocks
    shapelet_mfma_kernel<<<grid, dim3(NTH), 0, stream>>>(x, shp, pen, ss_ws, out);
}